// Round 14
// baseline (461.623 us; speedup 1.0000x reference)
//
#include <hip/hip_runtime.h>
#include <math.h>

#define BB 2
#define CC 96
#define HH 128
#define WW 128
#define PS 8
#define HP 16
#define WP 16
#define NPATCH 256
#define EE 96
#define FF 2048
#define DH 48
#define DIN 192
#define DR 6
#define DS 16
#define LL 16384
#define NCHUNK 512
#define CLEN 32
#define NSEG 16
#define SEGC 32
#define KTOT 6144
#define KSPLIT 32
#define KSL 192

// ---------------- helpers ----------------
__device__ __forceinline__ float sigmoid_acc(float x){ return 1.f/(1.f+expf(-x)); }
__device__ __forceinline__ float sigmoid_fast(float x){ return 1.f/(1.f+__expf(-x)); }

// ---------------- K1: antialiased bilinear resize of pos_embed 28x28 -> 16x16 ----------------
__global__ void k_resize_pe(const float* __restrict__ pos, float* __restrict__ pe16){
  int n = blockIdx.x;
  int oi = n / WP, oj = n % WP;
  int e = threadIdx.x;
  const float inv = 1.75f;
  float sfi = (oi + 0.5f)*inv - 0.5f;
  float sfj = (oj + 0.5f)*inv - 0.5f;
  int i0 = max(0, (int)ceilf(sfi - inv)), i1 = min(27, (int)floorf(sfi + inv));
  int j0 = max(0, (int)ceilf(sfj - inv)), j1 = min(27, (int)floorf(sfj + inv));
  float si = 0.f, sj = 0.f;
  for(int j=i0;j<=i1;j++) si += fmaxf(0.f, 1.f - fabsf(sfi - (float)j)/inv);
  for(int j=j0;j<=j1;j++) sj += fmaxf(0.f, 1.f - fabsf(sfj - (float)j)/inv);
  float acc = 0.f;
  for(int ji=i0;ji<=i1;ji++){
    float wv = fmaxf(0.f, 1.f - fabsf(sfi - (float)ji)/inv) / si;
    for(int jj=j0;jj<=j1;jj++){
      float wu = fmaxf(0.f, 1.f - fabsf(sfj - (float)jj)/inv);
      acc += wv * (wu/sj) * pos[(ji*28+jj)*EE + e];
    }
  }
  pe16[n*EE + e] = acc;
}

// ---------------- K2a: transpose vit proj weight ----------------
__global__ void k_wtr(const float* __restrict__ vw, float* __restrict__ Wt){
  __shared__ float t[64*97];
  int k0 = blockIdx.x*64;
  int tid = threadIdx.x;
  for(int i=tid;i<64*EE;i+=256){
    int e = i>>6, kk = i&63;
    t[kk*97 + e] = vw[(size_t)e*KTOT + k0 + kk];
  }
  __syncthreads();
  for(int i=tid;i<64*EE;i+=256){
    int kk = i/EE, e = i%EE;
    Wt[(size_t)(k0+kk)*EE + e] = t[kk*97 + e];
  }
}

// ---------------- K2b: split-K patch projection GEMM ----------------
__global__ __launch_bounds__(384) void k_pproj(const float* __restrict__ x,
    const float* __restrict__ Wt, float* __restrict__ part){
  __shared__ float As[16*196];
  int bidx = blockIdx.x;
  int ks = bidx & (KSPLIT-1);
  int pb = bidx >> 5;
  int b = pb >> 4, pi = pb & 15;
  int c0 = ks*3;
  int tid = threadIdx.x;
  for(int i=tid;i<24*128;i+=384){
    int row = i>>7;
    int col = i&127;
    int cl = row>>3, dr = row&7;
    float v = x[(((size_t)(b*CC + c0+cl))<<14) + (size_t)((pi*PS+dr)<<7) + col];
    As[(col>>3)*196 + cl*64 + dr*8 + (col&7)] = v;
  }
  __syncthreads();
  int e = tid % EE;
  int pq = tid / EE;
  const float* wp = Wt + (size_t)(ks*KSL)*EE + e;
  float acc0=0.f, acc1=0.f, acc2=0.f, acc3=0.f;
  const float4* A0 = (const float4*)(As + (pq*4+0)*196);
  const float4* A1 = (const float4*)(As + (pq*4+1)*196);
  const float4* A2 = (const float4*)(As + (pq*4+2)*196);
  const float4* A3 = (const float4*)(As + (pq*4+3)*196);
  #pragma unroll 4
  for(int k4=0;k4<48;k4++){
    float w0 = wp[(k4*4+0)*EE];
    float w1 = wp[(k4*4+1)*EE];
    float w2 = wp[(k4*4+2)*EE];
    float w3 = wp[(k4*4+3)*EE];
    float4 a;
    a = A0[k4]; acc0 += a.x*w0 + a.y*w1 + a.z*w2 + a.w*w3;
    a = A1[k4]; acc1 += a.x*w0 + a.y*w1 + a.z*w2 + a.w*w3;
    a = A2[k4]; acc2 += a.x*w0 + a.y*w1 + a.z*w2 + a.w*w3;
    a = A3[k4]; acc3 += a.x*w0 + a.y*w1 + a.z*w2 + a.w*w3;
  }
  size_t gp0 = (size_t)b*NPATCH + pi*WP + pq*4;
  part[((size_t)ks*512 + gp0+0)*EE + e] = acc0;
  part[((size_t)ks*512 + gp0+1)*EE + e] = acc1;
  part[((size_t)ks*512 + gp0+2)*EE + e] = acc2;
  part[((size_t)ks*512 + gp0+3)*EE + e] = acc3;
}

// ---------------- K2c: reduce partials + bias + pos + pvar + qkv (fused) ----------------
__global__ __launch_bounds__(320) void k_preduce_qkv(const float* __restrict__ part,
    const float* __restrict__ pb, const float* __restrict__ pe16,
    const float* __restrict__ inw, const float* __restrict__ inb,
    float* __restrict__ patches, float* __restrict__ pvar, float* __restrict__ qkv){
  int gp = blockIdx.x;
  int n = gp % NPATCH;
  int tid = threadIdx.x;  // 320
  __shared__ float a[EE];
  __shared__ float ps[2], pq2[2];
  float v = 0.f;
  if(tid < EE){
    float s = 0.f;
    #pragma unroll 8
    for(int ks=0;ks<KSPLIT;ks++) s += part[((size_t)ks*512 + gp)*EE + tid];
    v = s + pb[tid] + 0.1f*pe16[n*EE + tid];
    a[tid] = v;
    patches[(size_t)gp*EE + tid] = v;
  }
  if(tid < 128){
    float sv = v, sq = v*v;
    for(int off=32; off>0; off>>=1){ sv += __shfl_xor(sv, off); sq += __shfl_xor(sq, off); }
    if((tid&63)==0){ ps[tid>>6]=sv; pq2[tid>>6]=sq; }
  }
  __syncthreads();
  if(tid==0){
    float s = ps[0]+ps[1], qq = pq2[0]+pq2[1];
    float mu = s/EE;
    pvar[gp] = (qq - EE*mu*mu)/(EE-1);
  }
  if(tid < 288){
    const float4* ar = (const float4*)a;
    const float4* wr = (const float4*)(inw + (size_t)tid*EE);
    float4 s4 = {0.f,0.f,0.f,0.f};
    #pragma unroll
    for(int k=0;k<24;k++){
      float4 av=ar[k], wv=wr[k];
      s4.x += av.x*wv.x; s4.y += av.y*wv.y; s4.z += av.z*wv.z; s4.w += av.w*wv.w;
    }
    qkv[(size_t)gp*288 + tid] = inb[tid] + (s4.x+s4.y)+(s4.z+s4.w);
  }
}

// ---------------- K4: attention (both heads) + out-proj + residual + LN1, fused ----------------
__global__ __launch_bounds__(256) void k_attn_ln1(const float* __restrict__ qkv,
    const float* __restrict__ ow, const float* __restrict__ ob,
    const float* __restrict__ patches, const float* __restrict__ lw,
    const float* __restrict__ lb, float* __restrict__ src1){
  int gb = blockIdx.x;
  int i = gb & 255, b = gb >> 8;
  int tid = threadIdx.x;
  __shared__ float q[EE];
  __shared__ float2 red[NPATCH];
  __shared__ float p0[NPATCH], p1[NPATCH];
  __shared__ float part[2][EE];
  __shared__ float ctxs[EE];
  __shared__ float ps[2], pq2[2], st[2];
  const float* base = qkv + (size_t)b*NPATCH*288;
  if(tid < EE) q[tid] = base[(size_t)i*288 + tid];
  __syncthreads();
  float sc0, sc1;
  {
    const float4* krow = (const float4*)(base + (size_t)tid*288 + 96);
    const float4* q4 = (const float4*)q;
    float4 a0 = {0.f,0.f,0.f,0.f}, a1 = {0.f,0.f,0.f,0.f};
    #pragma unroll
    for(int k=0;k<12;k++){
      float4 kv=krow[k], qv=q4[k];
      a0.x += qv.x*kv.x; a0.y += qv.y*kv.y; a0.z += qv.z*kv.z; a0.w += qv.w*kv.w;
    }
    #pragma unroll
    for(int k=12;k<24;k++){
      float4 kv=krow[k], qv=q4[k];
      a1.x += qv.x*kv.x; a1.y += qv.y*kv.y; a1.z += qv.z*kv.z; a1.w += qv.w*kv.w;
    }
    sc0 = ((a0.x+a0.y)+(a0.z+a0.w)) * 0.14433756729740643f;
    sc1 = ((a1.x+a1.y)+(a1.z+a1.w)) * 0.14433756729740643f;
  }
  red[tid] = make_float2(sc0, sc1); __syncthreads();
  for(int stp=128; stp>0; stp>>=1){
    if(tid<stp){ float2 o=red[tid+stp]; red[tid].x=fmaxf(red[tid].x,o.x); red[tid].y=fmaxf(red[tid].y,o.y); }
    __syncthreads();
  }
  float2 mx = red[0]; __syncthreads();
  float ev0 = expf(sc0 - mx.x), ev1 = expf(sc1 - mx.y);
  red[tid] = make_float2(ev0, ev1); __syncthreads();
  for(int stp=128; stp>0; stp>>=1){
    if(tid<stp){ float2 o=red[tid+stp]; red[tid].x+=o.x; red[tid].y+=o.y; }
    __syncthreads();
  }
  float2 dn = red[0]; __syncthreads();
  p0[tid] = ev0/dn.x; p1[tid] = ev1/dn.y;
  __syncthreads();
  if(tid < 192){
    int dd = tid % EE, jh = tid / EE;
    const float* vb = base + 192 + dd;
    const float* pp = (dd < DH) ? p0 : p1;
    float acc0 = 0.f, acc1 = 0.f;
    #pragma unroll 4
    for(int j=jh*128; j<jh*128+128; j+=2){
      acc0 += pp[j]*vb[(size_t)j*288];
      acc1 += pp[j+1]*vb[(size_t)(j+1)*288];
    }
    part[jh][dd] = acc0+acc1;
  }
  __syncthreads();
  if(tid < EE) ctxs[tid] = part[0][tid] + part[1][tid];
  __syncthreads();
  float o = 0.f;
  if(tid < EE){
    const float4* ar = (const float4*)ctxs;
    const float4* wr = (const float4*)(ow + (size_t)tid*EE);
    float4 s4 = {0.f,0.f,0.f,0.f};
    #pragma unroll
    for(int k=0;k<24;k++){
      float4 av=ar[k], wv=wr[k];
      s4.x += av.x*wv.x; s4.y += av.y*wv.y; s4.z += av.z*wv.z; s4.w += av.w*wv.w;
    }
    o = ob[tid] + (s4.x+s4.y)+(s4.z+s4.w) + patches[(size_t)gb*EE + tid];
  }
  if(tid < 128){
    float sv = o, sq = o*o;
    for(int off=32; off>0; off>>=1){ sv += __shfl_xor(sv, off); sq += __shfl_xor(sq, off); }
    if((tid&63)==0){ ps[tid>>6]=sv; pq2[tid>>6]=sq; }
  }
  __syncthreads();
  if(tid==0){
    float s = ps[0]+ps[1], qq = pq2[0]+pq2[1];
    float mu = s/EE;
    st[0]=mu; st[1]=rsqrtf(qq/EE - mu*mu + 1e-5f);
  }
  __syncthreads();
  if(tid < EE) src1[(size_t)gb*EE + tid] = (o-st[0])*st[1]*lw[tid] + lb[tid];
}

// ---------------- K6: fused FFN: FF1+ReLU (LDS) + FF2 + residual + LN2 + score ----------------
__global__ __launch_bounds__(512) void k_ffn(const float* __restrict__ src1,
    const float* __restrict__ w1, const float* __restrict__ b1,
    const float* __restrict__ w2, const float* __restrict__ b2,
    const float* __restrict__ lw, const float* __restrict__ lb,
    const float* __restrict__ sw, const float* __restrict__ sb,
    const float* __restrict__ pvar, float* __restrict__ fscore){
  __shared__ float hr[2][FF];       // 16 KB
  __shared__ float partl[8][EE];
  __shared__ float s2[2][EE];
  __shared__ float psr[2][2], pqr[2][2], str[2][2];
  int row0 = blockIdx.x*2; int tid = threadIdx.x;
  {
    const float4* a0 = (const float4*)(src1 + (size_t)row0*EE);
    const float4* a1 = (const float4*)(src1 + (size_t)(row0+1)*EE);
    for(int fo=0;fo<4;fo++){
      int f = fo*512 + tid;
      const float4* wr = (const float4*)(w1 + (size_t)f*EE);
      float bc = b1[f];
      float acc0=bc, acc1=bc;
      #pragma unroll
      for(int k=0;k<24;k++){
        float4 wv = wr[k];
        float4 av;
        av = a0[k]; acc0 += av.x*wv.x+av.y*wv.y+av.z*wv.z+av.w*wv.w;
        av = a1[k]; acc1 += av.x*wv.x+av.y*wv.y+av.z*wv.z+av.w*wv.w;
      }
      hr[0][f] = fmaxf(acc0, 0.f);
      hr[1][f] = fmaxf(acc1, 0.f);
    }
  }
  __syncthreads();
  if(tid < 384){
    int e = tid % EE, fg = tid / EE;
    const float4* wr = (const float4*)(w2 + (size_t)e*FF + fg*512);
    const float4* h0 = (const float4*)(hr[0] + fg*512);
    const float4* h1 = (const float4*)(hr[1] + fg*512);
    float acc0=0.f, acc1=0.f;
    #pragma unroll 4
    for(int k=0;k<128;k++){
      float4 wv = wr[k];
      float4 hv;
      hv = h0[k]; acc0 += hv.x*wv.x+hv.y*wv.y+hv.z*wv.z+hv.w*wv.w;
      hv = h1[k]; acc1 += hv.x*wv.x+hv.y*wv.y+hv.z*wv.z+hv.w*wv.w;
    }
    partl[0*4+fg][e] = acc0;
    partl[1*4+fg][e] = acc1;
  }
  __syncthreads();
  if(tid < 192){
    int r = tid / EE, e2 = tid % EE;
    float s = partl[r*4+0][e2] + partl[r*4+1][e2] + partl[r*4+2][e2] + partl[r*4+3][e2];
    s2[r][e2] = s + b2[e2] + src1[(size_t)(row0+r)*EE + e2];
  }
  __syncthreads();
  int g = tid >> 7, t = tid & 127;
  float v = 0.f;
  if(g < 2){
    v = (t < EE) ? s2[g][t] : 0.f;
    float sv = v, sq = v*v;
    for(int off=32; off>0; off>>=1){ sv += __shfl_xor(sv, off); sq += __shfl_xor(sq, off); }
    if((t&63)==0){ psr[g][t>>6]=sv; pqr[g][t>>6]=sq; }
  }
  __syncthreads();
  if(g < 2 && t == 0){
    float s = psr[g][0]+psr[g][1], qq = pqr[g][0]+pqr[g][1];
    float mu = s/EE;
    str[g][0]=mu; str[g][1]=rsqrtf(qq/EE - mu*mu + 1e-5f);
  }
  __syncthreads();
  if(g < 2){
    float o = (t < EE) ? ((v-str[g][0])*str[g][1]*lw[t] + lb[t]) * sw[t] : 0.f;
    for(int off=32; off>0; off>>=1) o += __shfl_xor(o, off);
    if((t&63)==0) psr[g][t>>6] = o;
  }
  __syncthreads();
  if(g < 2 && t == 0){
    float acc = psr[g][0]+psr[g][1] + sb[0];
    fscore[row0+g] = 0.7f*sigmoid_acc(acc) + 0.3f*sigmoid_acc(pvar[row0+g]*10.f);
  }
}

// ---------------- K8: fused traversal (blocks 0,1) + raster LN + in_proj (blocks 2..1025) ----------------
__global__ __launch_bounds__(768) void k_trav_fused(const float* __restrict__ fscore,
    const float* __restrict__ x, const float* __restrict__ pe,
    const float* __restrict__ nw, const float* __restrict__ nb,
    const float* __restrict__ w, int* __restrict__ pixmap,
    float* __restrict__ xx, float* __restrict__ z){
  __shared__ float fsl[NPATCH];
  __shared__ int   sidxl[NPATCH];
  __shared__ int   ordl[NPATCH];
  __shared__ float a[32*100];
  __shared__ float ps[12*384];
  int tid = threadIdx.x;
  if(blockIdx.x < 2){
    int b = blockIdx.x;
    int lane = tid;
    if(lane < 64){
      for(int k=lane;k<NPATCH;k+=64) fsl[k] = fscore[b*NPATCH+k];
    }
    __syncthreads();
    if(lane < 64){
      float s0=fsl[lane], s1=fsl[64+lane], s2=fsl[128+lane], s3=fsl[192+lane];
      int i0=lane, i1=64+lane, i2=128+lane, i3=192+lane;
      int c0=0,c1=0,c2=0,c3=0;
      for(int j=0;j<NPATCH;j++){
        float sj=fsl[j];
        c0 += (sj>s0 || (sj==s0 && j<i0)) ? 1:0;
        c1 += (sj>s1 || (sj==s1 && j<i1)) ? 1:0;
        c2 += (sj>s2 || (sj==s2 && j<i2)) ? 1:0;
        c3 += (sj>s3 || (sj==s3 && j<i3)) ? 1:0;
      }
      sidxl[c0]=i0; sidxl[c1]=i1; sidxl[c2]=i2; sidxl[c3]=i3;
    }
    __syncthreads();
    if(lane==0){
      int cur = sidxl[0];
      ordl[0] = cur;
      fsl[cur] = -1e30f;
      int ptr = 1;
      int jcand = sidxl[1];
      for(int step=1; step<NPATCH; step++){
        int ci = cur>>4, cj = cur&15;
        int a0 = (ci>0)  ? cur-16 : cur;
        int a1 = (ci<15) ? cur+16 : cur;
        int a2 = (cj>0)  ? cur-1  : cur;
        int a3 = (cj<15) ? cur+1  : cur;
        float n0 = fsl[a0];
        float n1 = fsl[a1];
        float n2 = fsl[a2];
        float n3 = fsl[a3];
        float bv = n0; int bi = a0;
        if(n1 > bv){ bv=n1; bi=a1; }
        if(n2 > bv){ bv=n2; bi=a2; }
        if(n3 > bv){ bv=n3; bi=a3; }
        int nxt = (bv > -1e29f) ? bi : jcand;
        fsl[nxt] = -1e30f;
        ordl[step] = nxt;
        cur = nxt;
        if(nxt == jcand && step < NPATCH-1){
          float jv;
          do { ptr++; jcand = sidxl[ptr]; jv = fsl[jcand]; } while(jv <= -1e29f);
        }
      }
    }
    __syncthreads();
    for(int l=tid; l<LL; l+=768){
      int r = l>>6, q = l&63;
      int p = ordl[r];
      pixmap[b*LL + l] = (((p>>4)*PS + (q>>3))<<7) + (p&15)*PS + (q&7);
    }
  } else {
    int rb = blockIdx.x - 2;
    int R0 = rb*32;
    int b = R0 >> 14;
    int p0 = R0 & 16383;
    for(int i=tid;i<3072;i+=768){
      int c = i>>5, pl = i&31;
      a[pl*100 + c] = x[(((size_t)(b*CC + c))<<14) + p0 + pl];
    }
    __syncthreads();
    for(int i=tid;i<3072;i+=768){
      int pl = i/96, c = i - pl*96;
      a[pl*100 + c] += pe[((size_t)b*(HH*WW) + p0 + pl)*CC + c];
    }
    __syncthreads();
    {
      int wid = tid>>6, lane = tid&63;
      for(int t=wid; t<32; t+=12){
        float v1 = a[t*100 + lane];
        float v2 = (lane<32) ? a[t*100 + 64 + lane] : 0.f;
        float sv = v1+v2, sq = v1*v1 + v2*v2;
        for(int off=32; off>0; off>>=1){ sv += __shfl_xor(sv, off); sq += __shfl_xor(sq, off); }
        float mu = sv/EE;
        float rs = rsqrtf(sq/EE - mu*mu + 1e-5f);
        a[t*100 + lane] = (v1-mu)*rs*nw[lane] + nb[lane];
        if(lane < 32) a[t*100 + 64 + lane] = (v2-mu)*rs*nw[64+lane] + nb[64+lane];
      }
    }
    __syncthreads();
    int kh = tid/384, col = tid - kh*384;
    float4 wv[12];
    const float4* wr4 = (const float4*)(w + (size_t)col*EE + kh*48);
    #pragma unroll
    for(int i=0;i<12;i++) wv[i] = wr4[i];
    #pragma unroll
    for(int g=0; g<3; g++){
      float acc[12];
      #pragma unroll
      for(int r=0;r<12;r++){
        int gi = g*12 + r;
        if(gi < 32){
          const float4* ar = (const float4*)(a + gi*100 + kh*48);
          float4 s4 = {0.f,0.f,0.f,0.f};
          #pragma unroll
          for(int i=0;i<12;i++){
            float4 av = ar[i];
            s4.x += av.x*wv[i].x; s4.y += av.y*wv[i].y; s4.z += av.z*wv[i].z; s4.w += av.w*wv[i].w;
          }
          acc[r] = (s4.x+s4.y)+(s4.z+s4.w);
        } else acc[r] = 0.f;
      }
      if(kh==1){
        #pragma unroll
        for(int r=0;r<12;r++) if(g*12+r < 32) ps[r*384 + col] = acc[r];
      }
      __syncthreads();
      if(kh==0){
        #pragma unroll
        for(int r=0;r<12;r++){
          int gi = g*12 + r;
          if(gi < 32){
            float tot = acc[r] + ps[r*384 + col];
            if(col < DIN) xx[(size_t)(R0 + gi)*DIN + col] = tot;
            else          z [(size_t)(R0 + gi)*DIN + (col - DIN)] = tot;
          }
        }
      }
      __syncthreads();
    }
  }
}

// ---------------- K10: fused gather-conv + x_proj + dt + chunk-local scan ----------------
// dbl layout per row (40 floats): [0..5]=dt-rank, [8..23]=B, [24..39]=C
__global__ __launch_bounds__(256) void k_mamba1(const float* __restrict__ xx,
    const int* __restrict__ pixmap, const float* __restrict__ cw, const float* __restrict__ cb,
    const float* __restrict__ xpw, const float* __restrict__ dtw, const float* __restrict__ dtb,
    const float* __restrict__ Alog, float* __restrict__ xc, float* __restrict__ dblg,
    float* __restrict__ hend, float* __restrict__ sumdt){
  __shared__ int pixl[35];
  __shared__ float xxl[35*DIN];     // reused as dtl[32*DIN] later
  __shared__ float xcl[32*196];
  __shared__ float dbl[32*40];
  int blk = blockIdx.x; int b = blk>>9; int c = blk&511;
  int l0 = c*CLEN;
  int tid = threadIdx.x;
  if(tid < 35){
    int l = l0 - 3 + tid;
    pixl[tid] = (l >= 0) ? pixmap[b*LL + l] : 0;
  }
  __syncthreads();
  for(int i=tid; i<35*DIN; i+=256){
    int rr = i/DIN, d = i - rr*DIN;
    int l = l0 - 3 + rr;
    xxl[i] = (l >= 0) ? xx[((size_t)b*LL + pixl[rr])*DIN + d] : 0.f;
  }
  __syncthreads();
  for(int i=tid; i<32*DIN; i+=256){
    int rr = i/DIN, d = i - rr*DIN;
    float v = cb[d]
      + cw[d*4+0]*xxl[(rr+0)*DIN + d]
      + cw[d*4+1]*xxl[(rr+1)*DIN + d]
      + cw[d*4+2]*xxl[(rr+2)*DIN + d]
      + cw[d*4+3]*xxl[(rr+3)*DIN + d];
    float sv = v * sigmoid_fast(v);
    xcl[rr*196 + d] = sv;
    xc[((size_t)b*LL + l0 + rr)*DIN + d] = sv;
  }
  __syncthreads();
  // x_proj: 32 rows x 38 outs
  for(int task=tid; task<32*38; task+=256){
    int r = task & 31, o = task >> 5;
    const float4* wr = (const float4*)(xpw + (size_t)o*DIN);
    const float4* ar = (const float4*)(xcl + r*196);
    float4 s4 = {0.f,0.f,0.f,0.f};
    #pragma unroll
    for(int k=0;k<48;k++){
      float4 av=ar[k], wv=wr[k];
      s4.x += av.x*wv.x; s4.y += av.y*wv.y; s4.z += av.z*wv.z; s4.w += av.w*wv.w;
    }
    float val = (s4.x+s4.y)+(s4.z+s4.w);
    int om = (o<6) ? o : o+2;
    dbl[r*40 + om] = val;
    dblg[((size_t)b*LL + l0 + r)*40 + om] = val;
  }
  __syncthreads();
  // dt = softplus(dbl[0..6)*dtw + dtb)  -> dtl (reuse xxl)
  float* dtl = xxl;
  for(int i=tid; i<32*DIN; i+=256){
    int rr = i/DIN, d = i - rr*DIN;
    float acc = dtb[d];
    #pragma unroll
    for(int j=0;j<DR;j++) acc += dbl[rr*40+j]*dtw[d*DR+j];
    dtl[rr*DIN + d] = fmaxf(acc, 0.f) + log1pf(__expf(-fabsf(acc)));
  }
  __syncthreads();
  // chunk-local scan (scan1)
  if(tid < DIN){
    int d = tid;
    float A[16];
    {
      const float4* a4 = (const float4*)(Alog + d*DS);
      #pragma unroll
      for(int i=0;i<4;i++){
        float4 v = a4[i];
        A[i*4+0]=-expf(v.x); A[i*4+1]=-expf(v.y); A[i*4+2]=-expf(v.z); A[i*4+3]=-expf(v.w);
      }
    }
    float h[16];
    #pragma unroll
    for(int s=0;s<16;s++) h[s]=0.f;
    float sd = 0.f;
    for(int t=0;t<CLEN;t++){
      float dtv = dtl[t*DIN + d];
      float xv  = xcl[t*196 + d];
      const float4* bp4 = (const float4*)(dbl + t*40 + 8);
      float4 b0=bp4[0], b1=bp4[1], b2=bp4[2], b3=bp4[3];
      float e[16];
      #pragma unroll
      for(int s=0;s<16;s++) e[s] = __expf(dtv*A[s]);
      float Bv[16] = {b0.x,b0.y,b0.z,b0.w,b1.x,b1.y,b1.z,b1.w,b2.x,b2.y,b2.z,b2.w,b3.x,b3.y,b3.z,b3.w};
      float dx = dtv*xv; sd += dtv;
      #pragma unroll
      for(int s=0;s<16;s++) h[s] = e[s]*h[s] + dx*Bv[s];
    }
    size_t o = ((size_t)c*BB + b)*DIN + d;
    float4* hp = (float4*)(hend + o*DS);
    hp[0] = make_float4(h[0],h[1],h[2],h[3]);
    hp[1] = make_float4(h[4],h[5],h[6],h[7]);
    hp[2] = make_float4(h[8],h[9],h[10],h[11]);
    hp[3] = make_float4(h[12],h[13],h[14],h[15]);
    sumdt[o] = sd;
  }
}

// ---------------- K14a: segment-local chunk scan ----------------
__global__ __launch_bounds__(256) void k_scan2a(const float* __restrict__ hend,
    const float* __restrict__ sumdt, const float* __restrict__ Alog,
    float* __restrict__ segP, float* __restrict__ segH){
  int g = blockIdx.x*256 + threadIdx.x;
  int seg = g / 6144; int r = g % 6144;
  int b = r / 3072; int d = (r % 3072) >> 4; int s = r & 15;
  float A = -expf(Alog[d*DS + s]);
  float P = 1.f, H = 0.f;
  int c0 = seg*SEGC;
  for(int cc=0; cc<SEGC; cc+=4){
    float sd[4], he[4];
    #pragma unroll
    for(int j=0;j<4;j++){
      size_t o = ((size_t)(c0+cc+j)*BB + b)*DIN + d;
      sd[j] = sumdt[o]; he[j] = hend[o*DS + s];
    }
    #pragma unroll
    for(int j=0;j<4;j++){
      float aa = __expf(A*sd[j]);
      H = aa*H + he[j]; P *= aa;
    }
  }
  segP[seg*6144 + r] = P; segH[seg*6144 + r] = H;
}

// ---------------- K14b: segment prefix ----------------
__global__ void k_scan2b(const float* __restrict__ segP, const float* __restrict__ segH,
                         float* __restrict__ segHin){
  int r = blockIdx.x*256 + threadIdx.x;
  float P[NSEG], H[NSEG];
  #pragma unroll
  for(int sg=0; sg<NSEG; sg++){ P[sg]=segP[sg*6144+r]; H[sg]=segH[sg*6144+r]; }
  float h = 0.f;
  #pragma unroll
  for(int sg=0; sg<NSEG; sg++){
    segHin[sg*6144 + r] = h;
    h = P[sg]*h + H[sg];
  }
}

// ---------------- K14c: replay segment, write hin in-place into hend ----------------
__global__ __launch_bounds__(256) void k_scan2c(float* __restrict__ hend,
    const float* __restrict__ sumdt, const float* __restrict__ Alog,
    const float* __restrict__ segHin){
  int g = blockIdx.x*256 + threadIdx.x;
  int seg = g / 6144; int r = g % 6144;
  int b = r / 3072; int d = (r % 3072) >> 4; int s = r & 15;
  float A = -expf(Alog[d*DS + s]);
  float h = segHin[seg*6144 + r];
  int c0 = seg*SEGC;
  for(int cc=0; cc<SEGC; cc+=4){
    float sd[4], he[4]; size_t oo[4];
    #pragma unroll
    for(int j=0;j<4;j++){
      oo[j] = ((size_t)(c0+cc+j)*BB + b)*DIN + d;
      sd[j] = sumdt[oo[j]]; he[j] = hend[oo[j]*DS + s];
    }
    #pragma unroll
    for(int j=0;j<4;j++){
      hend[oo[j]*DS + s] = h;
      float aa = __expf(A*sd[j]);
      h = aa*h + he[j];
    }
  }
}

// ---------------- K15: final scan + gate (dt/B/C recomputed from dbl; z gathered via pixmap) ----------------
__global__ __launch_bounds__(192) void k_scan3(const float* __restrict__ xc,
    const float* __restrict__ dblg, const float* __restrict__ dtw, const float* __restrict__ dtb,
    const float* __restrict__ Alog, const float* __restrict__ hin,
    const float* __restrict__ Dskip, const int* __restrict__ pixmap,
    float* __restrict__ z){
  __shared__ float dbll[32*40];
  __shared__ int pixs[CLEN];
  int blk = blockIdx.x;
  int b = blk >> 9, c = blk & 511;
  int d = threadIdx.x;
  for(int i=d; i<32*40; i+=192) dbll[i] = dblg[((size_t)b*LL + c*CLEN)*40 + i];
  if(d < CLEN) pixs[d] = pixmap[b*LL + c*CLEN + d];
  float A[16];
  {
    const float4* a4 = (const float4*)(Alog + d*DS);
    #pragma unroll
    for(int i=0;i<4;i++){
      float4 v = a4[i];
      A[i*4+0]=-expf(v.x); A[i*4+1]=-expf(v.y); A[i*4+2]=-expf(v.z); A[i*4+3]=-expf(v.w);
    }
  }
  size_t o = ((size_t)c*BB + b)*DIN + d;
  float h[16];
  {
    const float4* hi = (const float4*)(hin + o*DS);
    #pragma unroll
    for(int i=0;i<4;i++){
      float4 v = hi[i];
      h[i*4+0]=v.x; h[i*4+1]=v.y; h[i*4+2]=v.z; h[i*4+3]=v.w;
    }
  }
  float dtwr[DR];
  #pragma unroll
  for(int j=0;j<DR;j++) dtwr[j] = dtw[d*DR+j];
  float dtbd = dtb[d];
  float Dv = Dskip[d];
  const float* xp = xc + ((size_t)b*LL + (size_t)c*CLEN)*DIN + d;
  __syncthreads();
  for(int t=0;t<CLEN;t++){
    float acc = dtbd;
    #pragma unroll
    for(int j=0;j<DR;j++) acc += dbll[t*40+j]*dtwr[j];
    float dtv = fmaxf(acc, 0.f) + log1pf(__expf(-fabsf(acc)));
    float xv  = xp[(size_t)t*DIN];
    size_t zrow = ((size_t)b*LL + pixs[t])*DIN + d;
    float zv  = z[zrow];
    const float4* bp4 = (const float4*)(dbll + t*40 + 8);
    const float4* cp4 = (const float4*)(dbll + t*40 + 24);
    float4 b0=bp4[0], b1=bp4[1], b2=bp4[2], b3=bp4[3];
    float4 c0=cp4[0], c1=cp4[1], c2=cp4[2], c3=cp4[3];
    float e[16];
    #pragma unroll
    for(int s=0;s<16;s++) e[s] = __expf(dtv*A[s]);
    float Bv[16] = {b0.x,b0.y,b0.z,b0.w,b1.x,b1.y,b1.z,b1.w,b2.x,b2.y,b2.z,b2.w,b3.x,b3.y,b3.z,b3.w};
    float Cv[16] = {c0.x,c0.y,c0.z,c0.w,c1.x,c1.y,c1.z,c1.w,c2.x,c2.y,c2.z,c2.w,c3.x,c3.y,c3.z,c3.w};
    float dx = dtv*xv;
    float y = 0.f;
    #pragma unroll
    for(int s=0;s<16;s++){ h[s] = e[s]*h[s] + dx*Bv[s]; y += h[s]*Cv[s]; }
    float yy = y + xv*Dv;
    z[zrow] = yy * (zv * sigmoid_fast(zv));
  }
}

// ---------------- K16: out_proj (192 -> 96) + direct transposed write to out ----------------
__global__ __launch_bounds__(384) void k_outproj(const float* __restrict__ g,
    const float* __restrict__ w, float* __restrict__ out){
  __shared__ float a[16*DIN];
  __shared__ float psA[16*EE];
  __shared__ float psB[16*EE];
  int rb = blockIdx.x; size_t row0 = (size_t)rb*16;
  int b = (int)(row0 >> 14);
  int pix0 = (int)(row0 & 16383);
  int tid = threadIdx.x;
  int col = tid % EE, kq = tid / EE;
  {
    const float4* src = (const float4*)(g + row0*DIN);
    float4* ad = (float4*)a;
    ad[tid] = src[tid];
    ad[tid+384] = src[tid+384];
  }
  float4 wv[12];
  const float4* wr4 = (const float4*)(w + (size_t)col*DIN + kq*48);
  #pragma unroll
  for(int i=0;i<12;i++) wv[i] = wr4[i];
  __syncthreads();
  float acc[16];
  for(int r=0;r<16;r++){
    const float4* ar = (const float4*)(a + r*DIN + kq*48);
    float4 s4 = {0.f,0.f,0.f,0.f};
    #pragma unroll
    for(int i=0;i<12;i++){
      float4 av = ar[i];
      s4.x += av.x*wv[i].x; s4.y += av.y*wv[i].y; s4.z += av.z*wv[i].z; s4.w += av.w*wv[i].w;
    }
    acc[r] = (s4.x+s4.y)+(s4.z+s4.w);
  }
  if(kq==1){
    for(int r=0;r<16;r++) psA[r*EE+col] = acc[r];
  }
  if(kq==3){
    for(int r=0;r<16;r++) psB[r*EE+col] = acc[r];
  }
  __syncthreads();
  if(kq==0){
    for(int r=0;r<16;r++) acc[r] += psA[r*EE+col];
  }
  if(kq==2){
    for(int r=0;r<16;r++) acc[r] += psB[r*EE+col];
  }
  __syncthreads();
  if(kq==2){
    for(int r=0;r<16;r++) psA[r*EE+col] = acc[r];
  }
  __syncthreads();
  if(kq==0){
    float4* ob4 = (float4*)(out + (((size_t)(b*CC + col))<<14) + pix0);
    ob4[0] = make_float4(acc[0]+psA[0*EE+col],  acc[1]+psA[1*EE+col],  acc[2]+psA[2*EE+col],  acc[3]+psA[3*EE+col]);
    ob4[1] = make_float4(acc[4]+psA[4*EE+col],  acc[5]+psA[5*EE+col],  acc[6]+psA[6*EE+col],  acc[7]+psA[7*EE+col]);
    ob4[2] = make_float4(acc[8]+psA[8*EE+col],  acc[9]+psA[9*EE+col],  acc[10]+psA[10*EE+col], acc[11]+psA[11*EE+col]);
    ob4[3] = make_float4(acc[12]+psA[12*EE+col], acc[13]+psA[13*EE+col], acc[14]+psA[14*EE+col], acc[15]+psA[15*EE+col]);
  }
}

// ---------------- launch ----------------
extern "C" void kernel_launch(void* const* d_in, const int* in_sizes, int n_in,
                              void* d_out, int out_size, void* d_ws, size_t ws_size,
                              hipStream_t stream){
  (void)in_sizes; (void)n_in; (void)out_size; (void)ws_size;
  const float* x    = (const float*)d_in[0];
  const float* pe   = (const float*)d_in[1];
  const float* pos  = (const float*)d_in[2];
  const float* vw   = (const float*)d_in[3];
  const float* vb   = (const float*)d_in[4];
  const float* inw  = (const float*)d_in[5];
  const float* inb  = (const float*)d_in[6];
  const float* ow   = (const float*)d_in[7];
  const float* ob   = (const float*)d_in[8];
  const float* l1w  = (const float*)d_in[9];
  const float* l1b  = (const float*)d_in[10];
  const float* f1w  = (const float*)d_in[11];
  const float* f1b  = (const float*)d_in[12];
  const float* f2w  = (const float*)d_in[13];
  const float* f2b  = (const float*)d_in[14];
  const float* l2w  = (const float*)d_in[15];
  const float* l2b  = (const float*)d_in[16];
  const float* sw   = (const float*)d_in[17];
  const float* sb   = (const float*)d_in[18];
  const float* nw   = (const float*)d_in[19];
  const float* nb   = (const float*)d_in[20];
  const float* ipw  = (const float*)d_in[21];
  const float* cw   = (const float*)d_in[22];
  const float* cb   = (const float*)d_in[23];
  const float* xpw  = (const float*)d_in[24];
  const float* dtw  = (const float*)d_in[25];
  const float* dtbp = (const float*)d_in[26];
  const float* alog = (const float*)d_in[27];
  const float* dsk  = (const float*)d_in[28];
  const float* opw  = (const float*)d_in[29];
  float* out = (float*)d_out;

  char* wsb = (char*)d_ws;
  size_t off = 0;
  auto alloc = [&](size_t nfloats)->void*{
    void* p = (void*)(wsb + off);
    off += ((nfloats*sizeof(float) + 255) & ~(size_t)255);
    return p;
  };
  float* pe16    = (float*)alloc(256*96);
  float* patches = (float*)alloc(512*96);
  float* pvar    = (float*)alloc(512);
  float* qkv     = (float*)alloc((size_t)512*288);
  float* src1    = (float*)alloc(512*96);
  float* fscore  = (float*)alloc(512);
  int*   pixmap  = (int*)  alloc((size_t)2*16384);
  float* tokens  = (float*)alloc((size_t)2*16384*96);
  float* xxb     = (float*)alloc((size_t)2*16384*192);
  float* zb      = (float*)alloc((size_t)2*16384*192);
  float* xcb     = (float*)alloc((size_t)2*16384*192);
  float* dblg    = (float*)alloc((size_t)2*16384*40);
  float* sumdt   = (float*)alloc((size_t)NCHUNK*2*192);
  float* segP    = (float*)alloc((size_t)NSEG*6144);
  float* segH    = (float*)alloc((size_t)NSEG*6144);
  float* segHin  = (float*)alloc((size_t)NSEG*6144);
  float* Wt    = xxb;     // dead before k_trav_fused writes xx
  float* part  = tokens;  // dead before k_mamba1 writes hend
  float* hend  = tokens;
  float* hin   = hend;    // scan2c writes hin in-place

  k_resize_pe   <<<256,   96, 0, stream>>>(pos, pe16);
  k_wtr         <<<96,   256, 0, stream>>>(vw, Wt);
  k_pproj       <<<1024, 384, 0, stream>>>(x, Wt, part);
  k_preduce_qkv <<<512,  320, 0, stream>>>(part, vb, pe16, inw, inb, patches, pvar, qkv);
  k_attn_ln1    <<<512,  256, 0, stream>>>(qkv, ow, ob, patches, l1w, l1b, src1);
  k_ffn         <<<256,  512, 0, stream>>>(src1, f1w, f1b, f2w, f2b, l2w, l2b, sw, sb, pvar, fscore);
  k_trav_fused  <<<1026, 768, 0, stream>>>(fscore, x, pe, nw, nb, ipw, pixmap, xxb, zb);
  k_mamba1      <<<1024, 256, 0, stream>>>(xxb, pixmap, cw, cb, xpw, dtw, dtbp, alog, xcb, dblg, hend, sumdt);
  k_scan2a      <<<384,  256, 0, stream>>>(hend, sumdt, alog, segP, segH);
  k_scan2b      <<<24,   256, 0, stream>>>(segP, segH, segHin);
  k_scan2c      <<<384,  256, 0, stream>>>(hend, sumdt, alog, segHin);
  k_scan3       <<<1024, 192, 0, stream>>>(xcb, dblg, dtw, dtbp, alog, hin, dsk, pixmap, zb);
  k_outproj     <<<2048, 384, 0, stream>>>(zb, opw, out);
}

// Round 15
// 431.167 us; speedup vs baseline: 1.0706x; 1.0706x over previous
//
#include <hip/hip_runtime.h>
#include <math.h>

#define BB 2
#define CC 96
#define HH 128
#define WW 128
#define PS 8
#define HP 16
#define WP 16
#define NPATCH 256
#define EE 96
#define FF 2048
#define DH 48
#define DIN 192
#define DR 6
#define DS 16
#define LL 16384
#define NCHUNK 512
#define CLEN 32
#define NSEG 16
#define SEGC 32
#define KTOT 6144
#define KSPLIT 32
#define KSL 192

// ---------------- helpers ----------------
__device__ __forceinline__ float sigmoid_acc(float x){ return 1.f/(1.f+expf(-x)); }
__device__ __forceinline__ float sigmoid_fast(float x){ return 1.f/(1.f+__expf(-x)); }

// ---------------- K1: antialiased bilinear resize of pos_embed 28x28 -> 16x16 ----------------
__global__ void k_resize_pe(const float* __restrict__ pos, float* __restrict__ pe16){
  int n = blockIdx.x;
  int oi = n / WP, oj = n % WP;
  int e = threadIdx.x;
  const float inv = 1.75f;
  float sfi = (oi + 0.5f)*inv - 0.5f;
  float sfj = (oj + 0.5f)*inv - 0.5f;
  int i0 = max(0, (int)ceilf(sfi - inv)), i1 = min(27, (int)floorf(sfi + inv));
  int j0 = max(0, (int)ceilf(sfj - inv)), j1 = min(27, (int)floorf(sfj + inv));
  float si = 0.f, sj = 0.f;
  for(int j=i0;j<=i1;j++) si += fmaxf(0.f, 1.f - fabsf(sfi - (float)j)/inv);
  for(int j=j0;j<=j1;j++) sj += fmaxf(0.f, 1.f - fabsf(sfj - (float)j)/inv);
  float acc = 0.f;
  for(int ji=i0;ji<=i1;ji++){
    float wv = fmaxf(0.f, 1.f - fabsf(sfi - (float)ji)/inv) / si;
    for(int jj=j0;jj<=j1;jj++){
      float wu = fmaxf(0.f, 1.f - fabsf(sfj - (float)jj)/inv);
      acc += wv * (wu/sj) * pos[(ji*28+jj)*EE + e];
    }
  }
  pe16[n*EE + e] = acc;
}

// ---------------- K2a: transpose vit proj weight ----------------
__global__ void k_wtr(const float* __restrict__ vw, float* __restrict__ Wt){
  __shared__ float t[64*97];
  int k0 = blockIdx.x*64;
  int tid = threadIdx.x;
  for(int i=tid;i<64*EE;i+=256){
    int e = i>>6, kk = i&63;
    t[kk*97 + e] = vw[(size_t)e*KTOT + k0 + kk];
  }
  __syncthreads();
  for(int i=tid;i<64*EE;i+=256){
    int kk = i/EE, e = i%EE;
    Wt[(size_t)(k0+kk)*EE + e] = t[kk*97 + e];
  }
}

// ---------------- K2b: split-K patch projection GEMM ----------------
__global__ __launch_bounds__(384) void k_pproj(const float* __restrict__ x,
    const float* __restrict__ Wt, float* __restrict__ part){
  __shared__ float As[16*196];
  int bidx = blockIdx.x;
  int ks = bidx & (KSPLIT-1);
  int pb = bidx >> 5;
  int b = pb >> 4, pi = pb & 15;
  int c0 = ks*3;
  int tid = threadIdx.x;
  for(int i=tid;i<24*128;i+=384){
    int row = i>>7;
    int col = i&127;
    int cl = row>>3, dr = row&7;
    float v = x[(((size_t)(b*CC + c0+cl))<<14) + (size_t)((pi*PS+dr)<<7) + col];
    As[(col>>3)*196 + cl*64 + dr*8 + (col&7)] = v;
  }
  __syncthreads();
  int e = tid % EE;
  int pq = tid / EE;
  const float* wp = Wt + (size_t)(ks*KSL)*EE + e;
  float acc0=0.f, acc1=0.f, acc2=0.f, acc3=0.f;
  const float4* A0 = (const float4*)(As + (pq*4+0)*196);
  const float4* A1 = (const float4*)(As + (pq*4+1)*196);
  const float4* A2 = (const float4*)(As + (pq*4+2)*196);
  const float4* A3 = (const float4*)(As + (pq*4+3)*196);
  #pragma unroll 4
  for(int k4=0;k4<48;k4++){
    float w0 = wp[(k4*4+0)*EE];
    float w1 = wp[(k4*4+1)*EE];
    float w2 = wp[(k4*4+2)*EE];
    float w3 = wp[(k4*4+3)*EE];
    float4 a;
    a = A0[k4]; acc0 += a.x*w0 + a.y*w1 + a.z*w2 + a.w*w3;
    a = A1[k4]; acc1 += a.x*w0 + a.y*w1 + a.z*w2 + a.w*w3;
    a = A2[k4]; acc2 += a.x*w0 + a.y*w1 + a.z*w2 + a.w*w3;
    a = A3[k4]; acc3 += a.x*w0 + a.y*w1 + a.z*w2 + a.w*w3;
  }
  size_t gp0 = (size_t)b*NPATCH + pi*WP + pq*4;
  part[((size_t)ks*512 + gp0+0)*EE + e] = acc0;
  part[((size_t)ks*512 + gp0+1)*EE + e] = acc1;
  part[((size_t)ks*512 + gp0+2)*EE + e] = acc2;
  part[((size_t)ks*512 + gp0+3)*EE + e] = acc3;
}

// ---------------- K2c: reduce partials + bias + pos + pvar + qkv (fused) ----------------
__global__ __launch_bounds__(320) void k_preduce_qkv(const float* __restrict__ part,
    const float* __restrict__ pb, const float* __restrict__ pe16,
    const float* __restrict__ inw, const float* __restrict__ inb,
    float* __restrict__ patches, float* __restrict__ pvar, float* __restrict__ qkv){
  int gp = blockIdx.x;
  int n = gp % NPATCH;
  int tid = threadIdx.x;  // 320
  __shared__ float a[EE];
  __shared__ float ps[2], pq2[2];
  float v = 0.f;
  if(tid < EE){
    float s = 0.f;
    #pragma unroll 8
    for(int ks=0;ks<KSPLIT;ks++) s += part[((size_t)ks*512 + gp)*EE + tid];
    v = s + pb[tid] + 0.1f*pe16[n*EE + tid];
    a[tid] = v;
    patches[(size_t)gp*EE + tid] = v;
  }
  if(tid < 128){
    float sv = v, sq = v*v;
    for(int off=32; off>0; off>>=1){ sv += __shfl_xor(sv, off); sq += __shfl_xor(sq, off); }
    if((tid&63)==0){ ps[tid>>6]=sv; pq2[tid>>6]=sq; }
  }
  __syncthreads();
  if(tid==0){
    float s = ps[0]+ps[1], qq = pq2[0]+pq2[1];
    float mu = s/EE;
    pvar[gp] = (qq - EE*mu*mu)/(EE-1);
  }
  if(tid < 288){
    const float4* ar = (const float4*)a;
    const float4* wr = (const float4*)(inw + (size_t)tid*EE);
    float4 s4 = {0.f,0.f,0.f,0.f};
    #pragma unroll
    for(int k=0;k<24;k++){
      float4 av=ar[k], wv=wr[k];
      s4.x += av.x*wv.x; s4.y += av.y*wv.y; s4.z += av.z*wv.z; s4.w += av.w*wv.w;
    }
    qkv[(size_t)gp*288 + tid] = inb[tid] + (s4.x+s4.y)+(s4.z+s4.w);
  }
}

// ---------------- K4: attention (both heads) + out-proj + residual + LN1, fused ----------------
__global__ __launch_bounds__(256) void k_attn_ln1(const float* __restrict__ qkv,
    const float* __restrict__ ow, const float* __restrict__ ob,
    const float* __restrict__ patches, const float* __restrict__ lw,
    const float* __restrict__ lb, float* __restrict__ src1){
  int gb = blockIdx.x;
  int i = gb & 255, b = gb >> 8;
  int tid = threadIdx.x;
  __shared__ float q[EE];
  __shared__ float2 red[NPATCH];
  __shared__ float p0[NPATCH], p1[NPATCH];
  __shared__ float part[2][EE];
  __shared__ float ctxs[EE];
  __shared__ float ps[2], pq2[2], st[2];
  const float* base = qkv + (size_t)b*NPATCH*288;
  if(tid < EE) q[tid] = base[(size_t)i*288 + tid];
  __syncthreads();
  float sc0, sc1;
  {
    const float4* krow = (const float4*)(base + (size_t)tid*288 + 96);
    const float4* q4 = (const float4*)q;
    float4 a0 = {0.f,0.f,0.f,0.f}, a1 = {0.f,0.f,0.f,0.f};
    #pragma unroll
    for(int k=0;k<12;k++){
      float4 kv=krow[k], qv=q4[k];
      a0.x += qv.x*kv.x; a0.y += qv.y*kv.y; a0.z += qv.z*kv.z; a0.w += qv.w*kv.w;
    }
    #pragma unroll
    for(int k=12;k<24;k++){
      float4 kv=krow[k], qv=q4[k];
      a1.x += qv.x*kv.x; a1.y += qv.y*kv.y; a1.z += qv.z*kv.z; a1.w += qv.w*kv.w;
    }
    sc0 = ((a0.x+a0.y)+(a0.z+a0.w)) * 0.14433756729740643f;
    sc1 = ((a1.x+a1.y)+(a1.z+a1.w)) * 0.14433756729740643f;
  }
  red[tid] = make_float2(sc0, sc1); __syncthreads();
  for(int stp=128; stp>0; stp>>=1){
    if(tid<stp){ float2 o=red[tid+stp]; red[tid].x=fmaxf(red[tid].x,o.x); red[tid].y=fmaxf(red[tid].y,o.y); }
    __syncthreads();
  }
  float2 mx = red[0]; __syncthreads();
  float ev0 = expf(sc0 - mx.x), ev1 = expf(sc1 - mx.y);
  red[tid] = make_float2(ev0, ev1); __syncthreads();
  for(int stp=128; stp>0; stp>>=1){
    if(tid<stp){ float2 o=red[tid+stp]; red[tid].x+=o.x; red[tid].y+=o.y; }
    __syncthreads();
  }
  float2 dn = red[0]; __syncthreads();
  p0[tid] = ev0/dn.x; p1[tid] = ev1/dn.y;
  __syncthreads();
  if(tid < 192){
    int dd = tid % EE, jh = tid / EE;
    const float* vb = base + 192 + dd;
    const float* pp = (dd < DH) ? p0 : p1;
    float acc0 = 0.f, acc1 = 0.f;
    #pragma unroll 4
    for(int j=jh*128; j<jh*128+128; j+=2){
      acc0 += pp[j]*vb[(size_t)j*288];
      acc1 += pp[j+1]*vb[(size_t)(j+1)*288];
    }
    part[jh][dd] = acc0+acc1;
  }
  __syncthreads();
  if(tid < EE) ctxs[tid] = part[0][tid] + part[1][tid];
  __syncthreads();
  float o = 0.f;
  if(tid < EE){
    const float4* ar = (const float4*)ctxs;
    const float4* wr = (const float4*)(ow + (size_t)tid*EE);
    float4 s4 = {0.f,0.f,0.f,0.f};
    #pragma unroll
    for(int k=0;k<24;k++){
      float4 av=ar[k], wv=wr[k];
      s4.x += av.x*wv.x; s4.y += av.y*wv.y; s4.z += av.z*wv.z; s4.w += av.w*wv.w;
    }
    o = ob[tid] + (s4.x+s4.y)+(s4.z+s4.w) + patches[(size_t)gb*EE + tid];
  }
  if(tid < 128){
    float sv = o, sq = o*o;
    for(int off=32; off>0; off>>=1){ sv += __shfl_xor(sv, off); sq += __shfl_xor(sq, off); }
    if((tid&63)==0){ ps[tid>>6]=sv; pq2[tid>>6]=sq; }
  }
  __syncthreads();
  if(tid==0){
    float s = ps[0]+ps[1], qq = pq2[0]+pq2[1];
    float mu = s/EE;
    st[0]=mu; st[1]=rsqrtf(qq/EE - mu*mu + 1e-5f);
  }
  __syncthreads();
  if(tid < EE) src1[(size_t)gb*EE + tid] = (o-st[0])*st[1]*lw[tid] + lb[tid];
}

// ---------------- K6: fused FFN: FF1+ReLU (LDS) + FF2 + residual + LN2 + score ----------------
__global__ __launch_bounds__(512) void k_ffn(const float* __restrict__ src1,
    const float* __restrict__ w1, const float* __restrict__ b1,
    const float* __restrict__ w2, const float* __restrict__ b2,
    const float* __restrict__ lw, const float* __restrict__ lb,
    const float* __restrict__ sw, const float* __restrict__ sb,
    const float* __restrict__ pvar, float* __restrict__ fscore){
  __shared__ float hr[2][FF];
  __shared__ float partl[8][EE];
  __shared__ float s2[2][EE];
  __shared__ float psr[2][2], pqr[2][2], str[2][2];
  int row0 = blockIdx.x*2; int tid = threadIdx.x;
  {
    const float4* a0 = (const float4*)(src1 + (size_t)row0*EE);
    const float4* a1 = (const float4*)(src1 + (size_t)(row0+1)*EE);
    for(int fo=0;fo<4;fo++){
      int f = fo*512 + tid;
      const float4* wr = (const float4*)(w1 + (size_t)f*EE);
      float bc = b1[f];
      float acc0=bc, acc1=bc;
      #pragma unroll
      for(int k=0;k<24;k++){
        float4 wv = wr[k];
        float4 av;
        av = a0[k]; acc0 += av.x*wv.x+av.y*wv.y+av.z*wv.z+av.w*wv.w;
        av = a1[k]; acc1 += av.x*wv.x+av.y*wv.y+av.z*wv.z+av.w*wv.w;
      }
      hr[0][f] = fmaxf(acc0, 0.f);
      hr[1][f] = fmaxf(acc1, 0.f);
    }
  }
  __syncthreads();
  if(tid < 384){
    int e = tid % EE, fg = tid / EE;
    const float4* wr = (const float4*)(w2 + (size_t)e*FF + fg*512);
    const float4* h0 = (const float4*)(hr[0] + fg*512);
    const float4* h1 = (const float4*)(hr[1] + fg*512);
    float acc0=0.f, acc1=0.f;
    #pragma unroll 4
    for(int k=0;k<128;k++){
      float4 wv = wr[k];
      float4 hv;
      hv = h0[k]; acc0 += hv.x*wv.x+hv.y*wv.y+hv.z*wv.z+hv.w*wv.w;
      hv = h1[k]; acc1 += hv.x*wv.x+hv.y*wv.y+hv.z*wv.z+hv.w*wv.w;
    }
    partl[0*4+fg][e] = acc0;
    partl[1*4+fg][e] = acc1;
  }
  __syncthreads();
  if(tid < 192){
    int r = tid / EE, e2 = tid % EE;
    float s = partl[r*4+0][e2] + partl[r*4+1][e2] + partl[r*4+2][e2] + partl[r*4+3][e2];
    s2[r][e2] = s + b2[e2] + src1[(size_t)(row0+r)*EE + e2];
  }
  __syncthreads();
  int g = tid >> 7, t = tid & 127;
  float v = 0.f;
  if(g < 2){
    v = (t < EE) ? s2[g][t] : 0.f;
    float sv = v, sq = v*v;
    for(int off=32; off>0; off>>=1){ sv += __shfl_xor(sv, off); sq += __shfl_xor(sq, off); }
    if((t&63)==0){ psr[g][t>>6]=sv; pqr[g][t>>6]=sq; }
  }
  __syncthreads();
  if(g < 2 && t == 0){
    float s = psr[g][0]+psr[g][1], qq = pqr[g][0]+pqr[g][1];
    float mu = s/EE;
    str[g][0]=mu; str[g][1]=rsqrtf(qq/EE - mu*mu + 1e-5f);
  }
  __syncthreads();
  if(g < 2){
    float o = (t < EE) ? ((v-str[g][0])*str[g][1]*lw[t] + lb[t]) * sw[t] : 0.f;
    for(int off=32; off>0; off>>=1) o += __shfl_xor(o, off);
    if((t&63)==0) psr[g][t>>6] = o;
  }
  __syncthreads();
  if(g < 2 && t == 0){
    float acc = psr[g][0]+psr[g][1] + sb[0];
    fscore[row0+g] = 0.7f*sigmoid_acc(acc) + 0.3f*sigmoid_acc(pvar[row0+g]*10.f);
  }
}

// ---------------- K8: fused traversal (blocks 0,1) + raster LN + in_proj (blocks 2..1025) ----------------
__global__ __launch_bounds__(768) void k_trav_fused(const float* __restrict__ fscore,
    const float* __restrict__ x, const float* __restrict__ pe,
    const float* __restrict__ nw, const float* __restrict__ nb,
    const float* __restrict__ w, int* __restrict__ pixmap,
    float* __restrict__ xx, float* __restrict__ z){
  __shared__ float fsl[NPATCH];
  __shared__ int   sidxl[NPATCH];
  __shared__ int   ordl[NPATCH];
  __shared__ float a[32*100];
  __shared__ float ps[12*384];
  int tid = threadIdx.x;
  if(blockIdx.x < 2){
    int b = blockIdx.x;
    int lane = tid;
    if(lane < 64){
      for(int k=lane;k<NPATCH;k+=64) fsl[k] = fscore[b*NPATCH+k];
    }
    __syncthreads();
    if(lane < 64){
      float s0=fsl[lane], s1=fsl[64+lane], s2=fsl[128+lane], s3=fsl[192+lane];
      int i0=lane, i1=64+lane, i2=128+lane, i3=192+lane;
      int c0=0,c1=0,c2=0,c3=0;
      for(int j=0;j<NPATCH;j++){
        float sj=fsl[j];
        c0 += (sj>s0 || (sj==s0 && j<i0)) ? 1:0;
        c1 += (sj>s1 || (sj==s1 && j<i1)) ? 1:0;
        c2 += (sj>s2 || (sj==s2 && j<i2)) ? 1:0;
        c3 += (sj>s3 || (sj==s3 && j<i3)) ? 1:0;
      }
      sidxl[c0]=i0; sidxl[c1]=i1; sidxl[c2]=i2; sidxl[c3]=i3;
    }
    __syncthreads();
    if(lane==0){
      int cur = sidxl[0];
      ordl[0] = cur;
      fsl[cur] = -1e30f;
      int ptr = 1;
      int jcand = sidxl[1];
      for(int step=1; step<NPATCH; step++){
        int ci = cur>>4, cj = cur&15;
        int a0 = (ci>0)  ? cur-16 : cur;
        int a1 = (ci<15) ? cur+16 : cur;
        int a2 = (cj>0)  ? cur-1  : cur;
        int a3 = (cj<15) ? cur+1  : cur;
        float n0 = fsl[a0];
        float n1 = fsl[a1];
        float n2 = fsl[a2];
        float n3 = fsl[a3];
        float bv = n0; int bi = a0;
        if(n1 > bv){ bv=n1; bi=a1; }
        if(n2 > bv){ bv=n2; bi=a2; }
        if(n3 > bv){ bv=n3; bi=a3; }
        int nxt = (bv > -1e29f) ? bi : jcand;
        fsl[nxt] = -1e30f;
        ordl[step] = nxt;
        cur = nxt;
        if(nxt == jcand && step < NPATCH-1){
          float jv;
          do { ptr++; jcand = sidxl[ptr]; jv = fsl[jcand]; } while(jv <= -1e29f);
        }
      }
    }
    __syncthreads();
    for(int l=tid; l<LL; l+=768){
      int r = l>>6, q = l&63;
      int p = ordl[r];
      pixmap[b*LL + l] = (((p>>4)*PS + (q>>3))<<7) + (p&15)*PS + (q&7);
    }
  } else {
    int rb = blockIdx.x - 2;
    int R0 = rb*32;
    int b = R0 >> 14;
    int p0 = R0 & 16383;
    for(int i=tid;i<3072;i+=768){
      int c = i>>5, pl = i&31;
      a[pl*100 + c] = x[(((size_t)(b*CC + c))<<14) + p0 + pl];
    }
    __syncthreads();
    for(int i=tid;i<3072;i+=768){
      int pl = i/96, c = i - pl*96;
      a[pl*100 + c] += pe[((size_t)b*(HH*WW) + p0 + pl)*CC + c];
    }
    __syncthreads();
    {
      int wid = tid>>6, lane = tid&63;
      for(int t=wid; t<32; t+=12){
        float v1 = a[t*100 + lane];
        float v2 = (lane<32) ? a[t*100 + 64 + lane] : 0.f;
        float sv = v1+v2, sq = v1*v1 + v2*v2;
        for(int off=32; off>0; off>>=1){ sv += __shfl_xor(sv, off); sq += __shfl_xor(sq, off); }
        float mu = sv/EE;
        float rs = rsqrtf(sq/EE - mu*mu + 1e-5f);
        a[t*100 + lane] = (v1-mu)*rs*nw[lane] + nb[lane];
        if(lane < 32) a[t*100 + 64 + lane] = (v2-mu)*rs*nw[64+lane] + nb[64+lane];
      }
    }
    __syncthreads();
    int kh = tid/384, col = tid - kh*384;
    float4 wv[12];
    const float4* wr4 = (const float4*)(w + (size_t)col*EE + kh*48);
    #pragma unroll
    for(int i=0;i<12;i++) wv[i] = wr4[i];
    #pragma unroll
    for(int g=0; g<3; g++){
      float acc[12];
      #pragma unroll
      for(int r=0;r<12;r++){
        int gi = g*12 + r;
        if(gi < 32){
          const float4* ar = (const float4*)(a + gi*100 + kh*48);
          float4 s4 = {0.f,0.f,0.f,0.f};
          #pragma unroll
          for(int i=0;i<12;i++){
            float4 av = ar[i];
            s4.x += av.x*wv[i].x; s4.y += av.y*wv[i].y; s4.z += av.z*wv[i].z; s4.w += av.w*wv[i].w;
          }
          acc[r] = (s4.x+s4.y)+(s4.z+s4.w);
        } else acc[r] = 0.f;
      }
      if(kh==1){
        #pragma unroll
        for(int r=0;r<12;r++) if(g*12+r < 32) ps[r*384 + col] = acc[r];
      }
      __syncthreads();
      if(kh==0){
        #pragma unroll
        for(int r=0;r<12;r++){
          int gi = g*12 + r;
          if(gi < 32){
            float tot = acc[r] + ps[r*384 + col];
            if(col < DIN) xx[(size_t)(R0 + gi)*DIN + col] = tot;
            else          z [(size_t)(R0 + gi)*DIN + (col - DIN)] = tot;
          }
        }
      }
      __syncthreads();
    }
  }
}

// ---------------- K10: gather-conv (k=4 causal over sequence) + silu ----------------
__global__ __launch_bounds__(256) void k_convgather(const float* __restrict__ xx,
    const int* __restrict__ pixmap, const float* __restrict__ cw,
    const float* __restrict__ cb, float* __restrict__ xc){
  __shared__ int pixl[35];
  __shared__ float xxl[35*DIN];
  int blk = blockIdx.x; int b = blk>>9; int l0 = (blk&511)*32;
  int tid = threadIdx.x;
  if(tid < 35){
    int l = l0 - 3 + tid;
    pixl[tid] = (l >= 0) ? pixmap[b*LL + l] : 0;
  }
  __syncthreads();
  for(int i=tid; i<35*DIN; i+=256){
    int rr = i/DIN, d = i - rr*DIN;
    int l = l0 - 3 + rr;
    xxl[i] = (l >= 0) ? xx[((size_t)b*LL + pixl[rr])*DIN + d] : 0.f;
  }
  __syncthreads();
  for(int i=tid; i<32*DIN; i+=256){
    int rr = i/DIN, d = i - rr*DIN;
    float v = cb[d]
      + cw[d*4+0]*xxl[(rr+0)*DIN + d]
      + cw[d*4+1]*xxl[(rr+1)*DIN + d]
      + cw[d*4+2]*xxl[(rr+2)*DIN + d]
      + cw[d*4+3]*xxl[(rr+3)*DIN + d];
    xc[((size_t)b*LL + l0 + rr)*DIN + d] = v * sigmoid_fast(v);
  }
}

// ---------------- K12: x_proj + dt proj + softplus ----------------
__global__ __launch_bounds__(320) void k_xproj(const float* __restrict__ xc, const float* __restrict__ xpw,
    const float* __restrict__ dtw, const float* __restrict__ dtb,
    float* __restrict__ dt, float* __restrict__ Bm, float* __restrict__ Cm){
  __shared__ float a[8][196];
  __shared__ float dbl[8][40];
  int rb = blockIdx.x; size_t row0 = (size_t)rb*8;
  int tid = threadIdx.x;
  for(int i=tid;i<8*DIN;i+=320){ int r=i/DIN, k=i%DIN; a[r][k] = xc[(row0+r)*DIN + k]; }
  __syncthreads();
  {
    int r = tid & 7, o = tid >> 3;
    if(o < 38){
      const float4* wr = (const float4*)(xpw + (size_t)o*DIN);
      const float4* ar = (const float4*)(a[r]);
      float4 s4 = {0.f,0.f,0.f,0.f};
      #pragma unroll
      for(int k=0;k<48;k++){
        float4 av=ar[k], wv=wr[k];
        s4.x += av.x*wv.x; s4.y += av.y*wv.y; s4.z += av.z*wv.z; s4.w += av.w*wv.w;
      }
      dbl[r][o] = (s4.x+s4.y)+(s4.z+s4.w);
    }
  }
  __syncthreads();
  for(int t=tid;t<8*DIN;t+=320){
    int r = t/DIN, d = t%DIN;
    float acc = dtb[d];
    #pragma unroll
    for(int j=0;j<DR;j++) acc += dbl[r][j]*dtw[d*DR+j];
    dt[(row0+r)*DIN + d] = fmaxf(acc, 0.f) + log1pf(__expf(-fabsf(acc)));
  }
  if(tid < 8*DS){
    int r = tid/DS, s = tid%DS;
    Bm[(row0+r)*DS + s] = dbl[r][6+s];
    Cm[(row0+r)*DS + s] = dbl[r][22+s];
  }
}

// ---------------- K13: chunk-local scan, 16 states per lane ----------------
__global__ __launch_bounds__(192) void k_scan1(const float* __restrict__ dt,
    const float* __restrict__ xc, const float* __restrict__ Bm,
    const float* __restrict__ Alog, float* __restrict__ hend, float* __restrict__ sumdt){
  int blk = blockIdx.x;
  int b = blk >> 9, c = blk & (NCHUNK-1);
  int d = threadIdx.x;
  float A[16];
  {
    const float4* a4 = (const float4*)(Alog + d*DS);
    #pragma unroll
    for(int i=0;i<4;i++){
      float4 v = a4[i];
      A[i*4+0]=-expf(v.x); A[i*4+1]=-expf(v.y); A[i*4+2]=-expf(v.z); A[i*4+3]=-expf(v.w);
    }
  }
  float h[16];
  #pragma unroll
  for(int s=0;s<16;s++) h[s]=0.f;
  float sd = 0.f;
  size_t base = (size_t)b*LL + (size_t)c*CLEN;
  const float* dp = dt + base*DIN + d;
  const float* xp = xc + base*DIN + d;
  const float4* bp = (const float4*)(Bm + base*DS);
  for(int t=0;t<CLEN;t++){
    float dtv = dp[(size_t)t*DIN];
    float xv  = xp[(size_t)t*DIN];
    float4 b0=bp[t*4+0], b1=bp[t*4+1], b2=bp[t*4+2], b3=bp[t*4+3];
    float e[16];
    #pragma unroll
    for(int s=0;s<16;s++) e[s] = __expf(dtv*A[s]);
    float Bv[16] = {b0.x,b0.y,b0.z,b0.w,b1.x,b1.y,b1.z,b1.w,b2.x,b2.y,b2.z,b2.w,b3.x,b3.y,b3.z,b3.w};
    float dx = dtv*xv; sd += dtv;
    #pragma unroll
    for(int s=0;s<16;s++) h[s] = e[s]*h[s] + dx*Bv[s];
  }
  size_t o = ((size_t)c*BB + b)*DIN + d;
  float4* hp = (float4*)(hend + o*DS);
  hp[0] = make_float4(h[0],h[1],h[2],h[3]);
  hp[1] = make_float4(h[4],h[5],h[6],h[7]);
  hp[2] = make_float4(h[8],h[9],h[10],h[11]);
  hp[3] = make_float4(h[12],h[13],h[14],h[15]);
  sumdt[o] = sd;
}

// ---------------- K14a: segment-local chunk scan ----------------
__global__ __launch_bounds__(256) void k_scan2a(const float* __restrict__ hend,
    const float* __restrict__ sumdt, const float* __restrict__ Alog,
    float* __restrict__ segP, float* __restrict__ segH){
  int g = blockIdx.x*256 + threadIdx.x;
  int seg = g / 6144; int r = g % 6144;
  int b = r / 3072; int d = (r % 3072) >> 4; int s = r & 15;
  float A = -expf(Alog[d*DS + s]);
  float P = 1.f, H = 0.f;
  int c0 = seg*SEGC;
  for(int cc=0; cc<SEGC; cc+=4){
    float sd[4], he[4];
    #pragma unroll
    for(int j=0;j<4;j++){
      size_t o = ((size_t)(c0+cc+j)*BB + b)*DIN + d;
      sd[j] = sumdt[o]; he[j] = hend[o*DS + s];
    }
    #pragma unroll
    for(int j=0;j<4;j++){
      float aa = __expf(A*sd[j]);
      H = aa*H + he[j]; P *= aa;
    }
  }
  segP[seg*6144 + r] = P; segH[seg*6144 + r] = H;
}

// ---------------- K14b: segment prefix ----------------
__global__ void k_scan2b(const float* __restrict__ segP, const float* __restrict__ segH,
                         float* __restrict__ segHin){
  int r = blockIdx.x*256 + threadIdx.x;
  float P[NSEG], H[NSEG];
  #pragma unroll
  for(int sg=0; sg<NSEG; sg++){ P[sg]=segP[sg*6144+r]; H[sg]=segH[sg*6144+r]; }
  float h = 0.f;
  #pragma unroll
  for(int sg=0; sg<NSEG; sg++){
    segHin[sg*6144 + r] = h;
    h = P[sg]*h + H[sg];
  }
}

// ---------------- K14c: replay segment, write hin in-place into hend ----------------
__global__ __launch_bounds__(256) void k_scan2c(float* __restrict__ hend,
    const float* __restrict__ sumdt, const float* __restrict__ Alog,
    const float* __restrict__ segHin){
  int g = blockIdx.x*256 + threadIdx.x;
  int seg = g / 6144; int r = g % 6144;
  int b = r / 3072; int d = (r % 3072) >> 4; int s = r & 15;
  float A = -expf(Alog[d*DS + s]);
  float h = segHin[seg*6144 + r];
  int c0 = seg*SEGC;
  for(int cc=0; cc<SEGC; cc+=4){
    float sd[4], he[4]; size_t oo[4];
    #pragma unroll
    for(int j=0;j<4;j++){
      oo[j] = ((size_t)(c0+cc+j)*BB + b)*DIN + d;
      sd[j] = sumdt[oo[j]]; he[j] = hend[oo[j]*DS + s];
    }
    #pragma unroll
    for(int j=0;j<4;j++){
      hend[oo[j]*DS + s] = h;
      float aa = __expf(A*sd[j]);
      h = aa*h + he[j];
    }
  }
}

// ---------------- K15: final scan + gate (z gathered via pixmap, gated in place) ----------------
__global__ __launch_bounds__(192) void k_scan3(const float* __restrict__ dt,
    const float* __restrict__ xc, const float* __restrict__ Bm, const float* __restrict__ Cm,
    const float* __restrict__ Alog, const float* __restrict__ hin,
    const float* __restrict__ Dskip, const int* __restrict__ pixmap,
    float* __restrict__ z){
  __shared__ int pixs[CLEN];
  int blk = blockIdx.x;
  int b = blk >> 9, c = blk & (NCHUNK-1);
  int d = threadIdx.x;
  if(d < CLEN) pixs[d] = pixmap[b*LL + c*CLEN + d];
  float A[16];
  {
    const float4* a4 = (const float4*)(Alog + d*DS);
    #pragma unroll
    for(int i=0;i<4;i++){
      float4 v = a4[i];
      A[i*4+0]=-expf(v.x); A[i*4+1]=-expf(v.y); A[i*4+2]=-expf(v.z); A[i*4+3]=-expf(v.w);
    }
  }
  size_t o = ((size_t)c*BB + b)*DIN + d;
  float h[16];
  {
    const float4* hi = (const float4*)(hin + o*DS);
    #pragma unroll
    for(int i=0;i<4;i++){
      float4 v = hi[i];
      h[i*4+0]=v.x; h[i*4+1]=v.y; h[i*4+2]=v.z; h[i*4+3]=v.w;
    }
  }
  float Dv = Dskip[d];
  size_t base = (size_t)b*LL + (size_t)c*CLEN;
  const float* dp = dt + base*DIN + d;
  const float* xp = xc + base*DIN + d;
  const float4* bp = (const float4*)(Bm + base*DS);
  const float4* cp = (const float4*)(Cm + base*DS);
  __syncthreads();
  for(int t=0;t<CLEN;t++){
    float dtv = dp[(size_t)t*DIN];
    float xv  = xp[(size_t)t*DIN];
    size_t zrow = ((size_t)b*LL + pixs[t])*DIN + d;
    float zv  = z[zrow];
    float4 b0=bp[t*4+0], b1=bp[t*4+1], b2=bp[t*4+2], b3=bp[t*4+3];
    float4 c0=cp[t*4+0], c1=cp[t*4+1], c2=cp[t*4+2], c3=cp[t*4+3];
    float e[16];
    #pragma unroll
    for(int s=0;s<16;s++) e[s] = __expf(dtv*A[s]);
    float Bv[16] = {b0.x,b0.y,b0.z,b0.w,b1.x,b1.y,b1.z,b1.w,b2.x,b2.y,b2.z,b2.w,b3.x,b3.y,b3.z,b3.w};
    float Cv[16] = {c0.x,c0.y,c0.z,c0.w,c1.x,c1.y,c1.z,c1.w,c2.x,c2.y,c2.z,c2.w,c3.x,c3.y,c3.z,c3.w};
    float dx = dtv*xv;
    float y = 0.f;
    #pragma unroll
    for(int s=0;s<16;s++){ h[s] = e[s]*h[s] + dx*Bv[s]; y += h[s]*Cv[s]; }
    float yy = y + xv*Dv;
    z[zrow] = yy * (zv * sigmoid_fast(zv));
  }
}

// ---------------- K16: out_proj (192 -> 96) + direct transposed write to out ----------------
__global__ __launch_bounds__(384) void k_outproj(const float* __restrict__ g,
    const float* __restrict__ w, float* __restrict__ out){
  __shared__ float a[16*DIN];
  __shared__ float psA[16*EE];
  __shared__ float psB[16*EE];
  int rb = blockIdx.x; size_t row0 = (size_t)rb*16;
  int b = (int)(row0 >> 14);
  int pix0 = (int)(row0 & 16383);
  int tid = threadIdx.x;
  int col = tid % EE, kq = tid / EE;
  {
    const float4* src = (const float4*)(g + row0*DIN);
    float4* ad = (float4*)a;
    ad[tid] = src[tid];
    ad[tid+384] = src[tid+384];
  }
  float4 wv[12];
  const float4* wr4 = (const float4*)(w + (size_t)col*DIN + kq*48);
  #pragma unroll
  for(int i=0;i<12;i++) wv[i] = wr4[i];
  __syncthreads();
  float acc[16];
  for(int r=0;r<16;r++){
    const float4* ar = (const float4*)(a + r*DIN + kq*48);
    float4 s4 = {0.f,0.f,0.f,0.f};
    #pragma unroll
    for(int i=0;i<12;i++){
      float4 av = ar[i];
      s4.x += av.x*wv[i].x; s4.y += av.y*wv[i].y; s4.z += av.z*wv[i].z; s4.w += av.w*wv[i].w;
    }
    acc[r] = (s4.x+s4.y)+(s4.z+s4.w);
  }
  if(kq==1){
    for(int r=0;r<16;r++) psA[r*EE+col] = acc[r];
  }
  if(kq==3){
    for(int r=0;r<16;r++) psB[r*EE+col] = acc[r];
  }
  __syncthreads();
  if(kq==0){
    for(int r=0;r<16;r++) acc[r] += psA[r*EE+col];
  }
  if(kq==2){
    for(int r=0;r<16;r++) acc[r] += psB[r*EE+col];
  }
  __syncthreads();
  if(kq==2){
    for(int r=0;r<16;r++) psA[r*EE+col] = acc[r];
  }
  __syncthreads();
  if(kq==0){
    float4* ob4 = (float4*)(out + (((size_t)(b*CC + col))<<14) + pix0);
    ob4[0] = make_float4(acc[0]+psA[0*EE+col],  acc[1]+psA[1*EE+col],  acc[2]+psA[2*EE+col],  acc[3]+psA[3*EE+col]);
    ob4[1] = make_float4(acc[4]+psA[4*EE+col],  acc[5]+psA[5*EE+col],  acc[6]+psA[6*EE+col],  acc[7]+psA[7*EE+col]);
    ob4[2] = make_float4(acc[8]+psA[8*EE+col],  acc[9]+psA[9*EE+col],  acc[10]+psA[10*EE+col], acc[11]+psA[11*EE+col]);
    ob4[3] = make_float4(acc[12]+psA[12*EE+col], acc[13]+psA[13*EE+col], acc[14]+psA[14*EE+col], acc[15]+psA[15*EE+col]);
  }
}

// ---------------- launch ----------------
extern "C" void kernel_launch(void* const* d_in, const int* in_sizes, int n_in,
                              void* d_out, int out_size, void* d_ws, size_t ws_size,
                              hipStream_t stream){
  (void)in_sizes; (void)n_in; (void)out_size; (void)ws_size;
  const float* x    = (const float*)d_in[0];
  const float* pe   = (const float*)d_in[1];
  const float* pos  = (const float*)d_in[2];
  const float* vw   = (const float*)d_in[3];
  const float* vb   = (const float*)d_in[4];
  const float* inw  = (const float*)d_in[5];
  const float* inb  = (const float*)d_in[6];
  const float* ow   = (const float*)d_in[7];
  const float* ob   = (const float*)d_in[8];
  const float* l1w  = (const float*)d_in[9];
  const float* l1b  = (const float*)d_in[10];
  const float* f1w  = (const float*)d_in[11];
  const float* f1b  = (const float*)d_in[12];
  const float* f2w  = (const float*)d_in[13];
  const float* f2b  = (const float*)d_in[14];
  const float* l2w  = (const float*)d_in[15];
  const float* l2b  = (const float*)d_in[16];
  const float* sw   = (const float*)d_in[17];
  const float* sb   = (const float*)d_in[18];
  const float* nw   = (const float*)d_in[19];
  const float* nb   = (const float*)d_in[20];
  const float* ipw  = (const float*)d_in[21];
  const float* cw   = (const float*)d_in[22];
  const float* cb   = (const float*)d_in[23];
  const float* xpw  = (const float*)d_in[24];
  const float* dtw  = (const float*)d_in[25];
  const float* dtbp = (const float*)d_in[26];
  const float* alog = (const float*)d_in[27];
  const float* dsk  = (const float*)d_in[28];
  const float* opw  = (const float*)d_in[29];
  float* out = (float*)d_out;

  char* wsb = (char*)d_ws;
  size_t off = 0;
  auto alloc = [&](size_t nfloats)->void*{
    void* p = (void*)(wsb + off);
    off += ((nfloats*sizeof(float) + 255) & ~(size_t)255);
    return p;
  };
  float* pe16    = (float*)alloc(256*96);
  float* patches = (float*)alloc(512*96);
  float* pvar    = (float*)alloc(512);
  float* qkv     = (float*)alloc((size_t)512*288);
  float* src1    = (float*)alloc(512*96);
  float* fscore  = (float*)alloc(512);
  int*   pixmap  = (int*)  alloc((size_t)2*16384);
  float* tokens  = (float*)alloc((size_t)2*16384*96);
  float* xxb     = (float*)alloc((size_t)2*16384*192);
  float* zb      = (float*)alloc((size_t)2*16384*192);
  float* xcb     = (float*)alloc((size_t)2*16384*192);
  float* Bmat    = (float*)alloc((size_t)2*16384*16);
  float* Cmat    = (float*)alloc((size_t)2*16384*16);
  float* sumdt   = (float*)alloc((size_t)NCHUNK*2*192);
  float* segP    = (float*)alloc((size_t)NSEG*6144);
  float* segH    = (float*)alloc((size_t)NSEG*6144);
  float* segHin  = (float*)alloc((size_t)NSEG*6144);
  float* dtbuf = xxb;     // xx dead after convgather; reuse for dt
  float* Wt    = xxb;     // dead before k_trav_fused writes xx
  float* part  = tokens;  // dead before scan1 writes hend
  float* hend  = tokens;
  float* hin   = hend;    // scan2c writes hin in-place

  k_resize_pe   <<<256,   96, 0, stream>>>(pos, pe16);
  k_wtr         <<<96,   256, 0, stream>>>(vw, Wt);
  k_pproj       <<<1024, 384, 0, stream>>>(x, Wt, part);
  k_preduce_qkv <<<512,  320, 0, stream>>>(part, vb, pe16, inw, inb, patches, pvar, qkv);
  k_attn_ln1    <<<512,  256, 0, stream>>>(qkv, ow, ob, patches, l1w, l1b, src1);
  k_ffn         <<<256,  512, 0, stream>>>(src1, f1w, f1b, f2w, f2b, l2w, l2b, sw, sb, pvar, fscore);
  k_trav_fused  <<<1026, 768, 0, stream>>>(fscore, x, pe, nw, nb, ipw, pixmap, xxb, zb);
  k_convgather  <<<1024, 256, 0, stream>>>(xxb, pixmap, cw, cb, xcb);
  k_xproj       <<<4096, 320, 0, stream>>>(xcb, xpw, dtw, dtbp, dtbuf, Bmat, Cmat);
  k_scan1       <<<1024, 192, 0, stream>>>(dtbuf, xcb, Bmat, alog, hend, sumdt);
  k_scan2a      <<<384,  256, 0, stream>>>(hend, sumdt, alog, segP, segH);
  k_scan2b      <<<24,   256, 0, stream>>>(segP, segH, segHin);
  k_scan2c      <<<384,  256, 0, stream>>>(hend, sumdt, alog, segHin);
  k_scan3       <<<1024, 192, 0, stream>>>(dtbuf, xcb, Bmat, Cmat, alog, hin, dsk, pixmap, zb);
  k_outproj     <<<2048, 384, 0, stream>>>(zb, opw, out);
}